// Round 1
// baseline (201.525 us; speedup 1.0000x reference)
//
#include <hip/hip_runtime.h>

// TrajLoss: sum over i of (x[i]-pred[i])^2 + (y[i]-pred[i+1])^2
// N = 16,777,216; pred has N+1 elements. Memory-bound streaming reduction.
//
// R5: algebraic re-split. Sum_i (y_i - p_{i+1})^2 == Sum_{j=1..N} (y_{j-1} - p_j)^2:
// thread owning pred[4i..4i+3] needs x4[i], p4[i] (aligned) and y[4i-1..4i+2].
// R6: all three streams nontemporal (zero reuse within one dispatch). 64.2 us.
// R7: grid 2048 (8 persistent blocks/CU, 8 chunks/thread, full unroll): 45.4 us.
// R8: grid 1024 (4 blocks/CU, 16 chunks/thread, unroll 16): 44.96 us.
// R9: DROP nontemporal on loads. Rationale: inputs total 201.3 MB < 256 MB
// Infinity Cache, and the bench re-dispatches the same kernel; rocprof showed
// FETCH_SIZE = 103 MB (~half of logical 201 MB) — i.e. half the stream was
// already cache-resident DESPITE the evict-first hint. nt is now fighting
// retention. Plain loads should let the full input set stay L3-resident
// across iterations. Predict FETCH_SIZE < 40 MB, kernel 45 -> ~32 us.

typedef float fx4 __attribute__((ext_vector_type(4)));

__global__ void TrajLoss_zero_kernel(float* out) {
    if (threadIdx.x == 0 && blockIdx.x == 0) out[0] = 0.0f;
}

__global__ __launch_bounds__(256) void TrajLoss_6141803233879_kernel(
    const float* __restrict__ pred,
    const float* __restrict__ x,
    const float* __restrict__ y,
    float* __restrict__ out,
    int n4,   // n / 4 (float4 count)
    int n)    // total elements
{
    const int tid    = blockIdx.x * blockDim.x + threadIdx.x;
    const int stride = gridDim.x * blockDim.x;

    float a0 = 0.0f, a1 = 0.0f, a2 = 0.0f, a3 = 0.0f;
    const fx4* x4 = (const fx4*)x;
    const fx4* p4 = (const fx4*)pred;

    int i = tid;

    if (tid == 0) {
        // Peel chunk 0 (rewrite terms j=0..3: dx_0..3, dy_1..3) + boundary j=N.
        float dx, dy;
        dx = x[0] - pred[0];                       a0 += dx*dx;
        dx = x[1] - pred[1]; dy = y[0] - pred[1];  a1 += dx*dx + dy*dy;
        dx = x[2] - pred[2]; dy = y[1] - pred[2];  a2 += dx*dx + dy*dy;
        dx = x[3] - pred[3]; dy = y[2] - pred[3];  a3 += dx*dx + dy*dy;
        if ((n & 3) == 0) {
            dy = y[n - 1] - pred[n];               a0 += dy*dy;   // rewrite j=N
        } else {
            // generic tail (dead for N=16.7M)
            dy = y[(n4 << 2) - 1] - pred[n4 << 2]; a0 += dy*dy;
            for (int j = n4 << 2; j < n; ++j) {
                dx = x[j] - pred[j];
                dy = y[j] - pred[j + 1];
                a0 += dx*dx + dy*dy;
            }
        }
        i += stride;   // thread 0 skips its first generic chunk (handled above)
    }

    #pragma unroll 16
    for (; i < n4; i += stride) {
        fx4 xv = x4[i];
        fx4 pa = p4[i];                               // pred[4i..4i+3]
        fx4 yb = *(const fx4*)(y + (i << 2) - 1);     // y[4i-1..4i+2]
        float dx, dy;
        dx = xv.x - pa.x; dy = yb.x - pa.x; a0 += dx*dx + dy*dy;
        dx = xv.y - pa.y; dy = yb.y - pa.y; a1 += dx*dx + dy*dy;
        dx = xv.z - pa.z; dy = yb.z - pa.z; a2 += dx*dx + dy*dy;
        dx = xv.w - pa.w; dy = yb.w - pa.w; a3 += dx*dx + dy*dy;
    }

    float acc = (a0 + a1) + (a2 + a3);

    // Wave-64 reduce
    #pragma unroll
    for (int off = 32; off > 0; off >>= 1)
        acc += __shfl_down(acc, off, 64);

    __shared__ float smem[4];   // 256 threads = 4 waves
    const int lane = threadIdx.x & 63;
    const int wave = threadIdx.x >> 6;
    if (lane == 0) smem[wave] = acc;
    __syncthreads();

    if (threadIdx.x == 0) {
        float s = smem[0] + smem[1] + smem[2] + smem[3];
        atomicAdd(out, s);   // device-scope by default on gfx950
    }
}

extern "C" void kernel_launch(void* const* d_in, const int* in_sizes, int n_in,
                              void* d_out, int out_size, void* d_ws, size_t ws_size,
                              hipStream_t stream) {
    const float* pred = (const float*)d_in[0];   // N+1 floats
    const float* x    = (const float*)d_in[1];   // N floats
    const float* y    = (const float*)d_in[2];   // N floats
    float* out = (float*)d_out;

    const int n  = in_sizes[1];
    const int n4 = n >> 2;

    TrajLoss_zero_kernel<<<1, 64, 0, stream>>>(out);

    const int block = 256;
    // 1024 blocks = 4 resident blocks/CU, persistent: 262,144 threads ->
    // exactly 16 float4 chunks/thread at N=16.7M.
    const int grid = 1024;
    TrajLoss_6141803233879_kernel<<<grid, block, 0, stream>>>(pred, x, y, out, n4, n);
}

// Round 3
// 187.762 us; speedup vs baseline: 1.0733x; 1.0733x over previous
//
#include <hip/hip_runtime.h>

// TrajLoss: sum over i of (x[i]-pred[i])^2 + (y[i]-pred[i+1])^2
// N = 16,777,216; pred has N+1 elements. Memory-bound streaming reduction.
//
// R5: algebraic re-split. Sum_i (y_i - p_{i+1})^2 == Sum_{j=1..N} (y_{j-1} - p_j)^2.
// R6: all three streams nontemporal. 64.2 us.
// R7: grid 2048 persistent. 45.4 us.  R8: grid 1024, unroll 16: 44.96 us.
// R9 FAILED: plain loads (L3-residency theory). FETCH_SIZE unchanged (~101 MB,
//    harness re-poison controls residency, not the hint) but 45->80 us: without
//    nt, 3 streams thrash the 4 MiB/XCD L2 (25 MB/XCD) and allocation churn
//    halves service rate. nt is LOAD-BEARING -> reverted, never remove.
// R10: alignment fix. At 45 us we are at 4.48/6.3 TB/s = 71% with HBM at 29%,
//    VALU 5%, occupancy flat vs grid -> transaction-rate bound. The y load at
//    (4i-1) straddles 64B lines (every 4th lane splits, 17 lines/wave vs 16):
//    ~2x request cost for 1 of 3 streams -> 3/4 efficiency -> 0.75*6.3 = 4.7
//    TB/s ~= measured. Fix: aligned y4[i] + __shfl_up(yv.w,1) for y[4i-1];
//    lane 0 of each wave does a 1-dword fixup load; chunk 0's missing dy'_0
//    term zeroed via ym1=pred[0]. Uniform trip count (shuffle lockstep).
// R11: R10 bench died with container failure (infra or fault). Audit found a
//    potential OOB: ternary `(i==0) ? pa.x : y[4i-1]` can be lowered to
//    load+cndmask under exec-mask predication -> issues y[-1] for tid 0.
//    Fix: clamp address to >=0 so the load is always in-bounds/speculatable,
//    then select. No other change; R10 prediction stands (~35 us).

typedef float fx4 __attribute__((ext_vector_type(4)));

__global__ void TrajLoss_zero_kernel(float* out) {
    if (threadIdx.x == 0 && blockIdx.x == 0) out[0] = 0.0f;
}

__global__ __launch_bounds__(256) void TrajLoss_6141803233879_kernel(
    const float* __restrict__ pred,
    const float* __restrict__ x,
    const float* __restrict__ y,
    float* __restrict__ out,
    int n4,   // n / 4 (float4 count)
    int n)    // total elements
{
    const int tid    = blockIdx.x * blockDim.x + threadIdx.x;
    const int stride = gridDim.x * blockDim.x;
    const int lane   = threadIdx.x & 63;

    float a0 = 0.0f, a1 = 0.0f, a2 = 0.0f, a3 = 0.0f;
    const fx4* x4 = (const fx4*)x;
    const fx4* p4 = (const fx4*)pred;
    const fx4* y4 = (const fx4*)y;

    if (tid == 0) {
        // Boundary term dy'_N = (y[n-1]-pred[n])^2, plus generic tail
        // (tail loop dead for N=16.7M where n%4==0).
        if ((n & 3) == 0) {
            float dN = y[n - 1] - pred[n];  a0 += dN * dN;
        } else {
            for (int j = n4 << 2; j < n; ++j) {
                float dx = x[j] - pred[j];  a0 += dx * dx;
                if (j >= 1) { float d2 = y[j - 1] - pred[j]; a0 += d2 * d2; }
            }
            float dN = y[n - 1] - pred[n];  a0 += dN * dN;
        }
    }

    #pragma unroll 16
    for (int i = tid; i < n4; i += stride) {
        fx4 xv = __builtin_nontemporal_load(x4 + i);   // x[4i..4i+3]
        fx4 pa = __builtin_nontemporal_load(p4 + i);   // pred[4i..4i+3]
        fx4 yv = __builtin_nontemporal_load(y4 + i);   // y[4i..4i+3]  (ALIGNED)

        // y[4i-1] comes from lane-1's yv.w (chunk i-1 is owned by lane-1:
        // uniform stride => lanes differ by exactly 1 chunk, lockstep k).
        float ym1 = __shfl_up(yv.w, 1, 64);
        if (lane == 0) {
            int idx = (i << 2) - 1;
            float yl = y[idx < 0 ? 0 : idx];     // clamped: always in-bounds
            ym1 = (i == 0) ? pa.x : yl;          // i==0: dy'_0 absent -> force 0
        }

        float dx, dy;
        dx = xv.x - pa.x; dy = ym1  - pa.x; a0 += dx*dx + dy*dy;
        dx = xv.y - pa.y; dy = yv.x - pa.y; a1 += dx*dx + dy*dy;
        dx = xv.z - pa.z; dy = yv.y - pa.z; a2 += dx*dx + dy*dy;
        dx = xv.w - pa.w; dy = yv.z - pa.w; a3 += dx*dx + dy*dy;
    }

    float acc = (a0 + a1) + (a2 + a3);

    // Wave-64 reduce
    #pragma unroll
    for (int off = 32; off > 0; off >>= 1)
        acc += __shfl_down(acc, off, 64);

    __shared__ float smem[4];   // 256 threads = 4 waves
    const int wave = threadIdx.x >> 6;
    if (lane == 0) smem[wave] = acc;
    __syncthreads();

    if (threadIdx.x == 0) {
        float s = smem[0] + smem[1] + smem[2] + smem[3];
        atomicAdd(out, s);   // device-scope by default on gfx950
    }
}

extern "C" void kernel_launch(void* const* d_in, const int* in_sizes, int n_in,
                              void* d_out, int out_size, void* d_ws, size_t ws_size,
                              hipStream_t stream) {
    const float* pred = (const float*)d_in[0];   // N+1 floats
    const float* x    = (const float*)d_in[1];   // N floats
    const float* y    = (const float*)d_in[2];   // N floats
    float* out = (float*)d_out;

    const int n  = in_sizes[1];
    const int n4 = n >> 2;

    TrajLoss_zero_kernel<<<1, 64, 0, stream>>>(out);

    const int block = 256;
    // 1024 blocks = 4 resident blocks/CU, persistent: 262,144 threads ->
    // exactly 16 float4 chunks/thread at N=16.7M.
    const int grid = 1024;
    TrajLoss_6141803233879_kernel<<<grid, block, 0, stream>>>(pred, x, y, out, n4, n);
}

// Round 4
// 181.421 us; speedup vs baseline: 1.1108x; 1.0350x over previous
//
#include <hip/hip_runtime.h>

// TrajLoss: sum over i of (x[i]-pred[i])^2 + (y[i]-pred[i+1])^2
// N = 16,777,216; pred has N+1 elements. Memory-bound streaming reduction.
//
// R5: algebraic re-split. Sum_i (y_i - p_{i+1})^2 == Sum_{j=1..N} (y_{j-1} - p_j)^2.
// R6: all three streams nontemporal. 64.2 us.
// R7: grid 2048 persistent. 45.4 us.  R8: grid 1024, unroll 16: 44.96 us.
// R9 FAILED: plain loads. FETCH_SIZE unchanged (~101 MB; harness re-poison
//    controls residency, not the hint) but 45->80 us: 3 streams thrash the
//    4 MiB/XCD L2. nt is LOAD-BEARING on the bulk streams.
// R10/R11 CONFOUNDED: aligned y + per-iter lane-0 fixup load. 48 us, but
//    VGPR 72 -> 16: the divergent in-loop branch+load killed the compiler's
//    load batching (MLP), the thing R7/R8's speed came from. Occupancy rose
//    22->32% yet perf dropped — this kernel lives on per-wave MLP.
//    Alignment theory NOT tested by R11.
// R12: clean test. Aligned y4[i] + shfl_up, edge values PRELOADED into a
//    static-index register array before the loop (16 divergent lane-0 loads,
//    cached not-nt so the main stream may L2-hit those lines). Inner loop is
//    branch-free: 3 nt loads + shfl + cndmask -> batching restored.
//    Validity check: VGPR must be back >= 64. If theory right: ~35-38 us.
//    If ~45 us with high VGPR: alignment refuted -> 4.5 TB/s plateau, stop.

typedef float fx4 __attribute__((ext_vector_type(4)));

__global__ void TrajLoss_zero_kernel(float* out) {
    if (threadIdx.x == 0 && blockIdx.x == 0) out[0] = 0.0f;
}

// ---------------- specialized: n%4==0, n4 == 16*stride ----------------
__global__ __launch_bounds__(256) void TrajLoss_6141803233879_kernel(
    const float* __restrict__ pred,
    const float* __restrict__ x,
    const float* __restrict__ y,
    float* __restrict__ out,
    int n)    // total elements; n4 = n/4 == 16 * gridDim*blockDim exactly
{
    const int tid    = blockIdx.x * blockDim.x + threadIdx.x;
    const int stride = gridDim.x * blockDim.x;
    const int lane   = threadIdx.x & 63;

    float a0 = 0.0f, a1 = 0.0f, a2 = 0.0f, a3 = 0.0f;
    const fx4* x4 = (const fx4*)x;
    const fx4* p4 = (const fx4*)pred;
    const fx4* y4 = (const fx4*)y;

    if (tid == 0) {
        // Boundary term dy'_N = (y[n-1]-pred[n])^2.
        float dN = y[n - 1] - pred[n];
        a0 += dN * dN;
    }

    // Preload lane-0 wave-edge values y[4*(tid+k*stride)-1] (static indices
    // only -> stays in registers). Other lanes never read edge[].
    float edge[16];
    if (lane == 0) {
        #pragma unroll
        for (int k = 0; k < 16; ++k) {
            int idx = ((tid + k * stride) << 2) - 1;
            edge[k] = y[idx < 0 ? 0 : idx];      // clamp: always in-bounds
        }
        if (tid == 0) edge[0] = pred[0];         // chunk 0: dy'_0 absent -> dy=0
    }

    #pragma unroll
    for (int k = 0; k < 16; ++k) {
        const int i = tid + k * stride;
        fx4 xv = __builtin_nontemporal_load(x4 + i);   // x[4i..4i+3]
        fx4 pa = __builtin_nontemporal_load(p4 + i);   // pred[4i..4i+3]
        fx4 yv = __builtin_nontemporal_load(y4 + i);   // y[4i..4i+3]  (ALIGNED)

        // y[4i-1]: lane-1's yv.w (lanes own consecutive chunks, lockstep k).
        float ym1 = __shfl_up(yv.w, 1, 64);
        ym1 = (lane == 0) ? edge[k] : ym1;             // branch-free select

        float dx, dy;
        dx = xv.x - pa.x; dy = ym1  - pa.x; a0 += dx*dx + dy*dy;
        dx = xv.y - pa.y; dy = yv.x - pa.y; a1 += dx*dx + dy*dy;
        dx = xv.z - pa.z; dy = yv.y - pa.z; a2 += dx*dx + dy*dy;
        dx = xv.w - pa.w; dy = yv.z - pa.w; a3 += dx*dx + dy*dy;
    }

    float acc = (a0 + a1) + (a2 + a3);

    #pragma unroll
    for (int off = 32; off > 0; off >>= 1)
        acc += __shfl_down(acc, off, 64);

    __shared__ float smem[4];
    const int wave = threadIdx.x >> 6;
    if (lane == 0) smem[wave] = acc;
    __syncthreads();

    if (threadIdx.x == 0) {
        float s = smem[0] + smem[1] + smem[2] + smem[3];
        atomicAdd(out, s);
    }
}

// ---------------- generic fallback: R8 kernel (proven 44.96 us) ----------------
__global__ __launch_bounds__(256) void TrajLoss_generic_kernel(
    const float* __restrict__ pred,
    const float* __restrict__ x,
    const float* __restrict__ y,
    float* __restrict__ out,
    int n4, int n)
{
    const int tid    = blockIdx.x * blockDim.x + threadIdx.x;
    const int stride = gridDim.x * blockDim.x;

    float a0 = 0.0f, a1 = 0.0f, a2 = 0.0f, a3 = 0.0f;
    const fx4* x4 = (const fx4*)x;
    const fx4* p4 = (const fx4*)pred;

    int i = tid;

    if (tid == 0) {
        float dx, dy;
        dx = x[0] - pred[0];                       a0 += dx*dx;
        dx = x[1] - pred[1]; dy = y[0] - pred[1];  a1 += dx*dx + dy*dy;
        dx = x[2] - pred[2]; dy = y[1] - pred[2];  a2 += dx*dx + dy*dy;
        dx = x[3] - pred[3]; dy = y[2] - pred[3];  a3 += dx*dx + dy*dy;
        if ((n & 3) == 0) {
            dy = y[n - 1] - pred[n];               a0 += dy*dy;
        } else {
            dy = y[(n4 << 2) - 1] - pred[n4 << 2]; a0 += dy*dy;
            for (int j = n4 << 2; j < n; ++j) {
                dx = x[j] - pred[j];
                dy = y[j] - pred[j + 1];
                a0 += dx*dx + dy*dy;
            }
        }
        i += stride;
    }

    #pragma unroll 16
    for (; i < n4; i += stride) {
        fx4 xv = __builtin_nontemporal_load(x4 + i);
        fx4 pa = __builtin_nontemporal_load(p4 + i);
        fx4 yb = __builtin_nontemporal_load((const fx4*)(y + (i << 2) - 1));
        float dx, dy;
        dx = xv.x - pa.x; dy = yb.x - pa.x; a0 += dx*dx + dy*dy;
        dx = xv.y - pa.y; dy = yb.y - pa.y; a1 += dx*dx + dy*dy;
        dx = xv.z - pa.z; dy = yb.z - pa.z; a2 += dx*dx + dy*dy;
        dx = xv.w - pa.w; dy = yb.w - pa.w; a3 += dx*dx + dy*dy;
    }

    float acc = (a0 + a1) + (a2 + a3);

    #pragma unroll
    for (int off = 32; off > 0; off >>= 1)
        acc += __shfl_down(acc, off, 64);

    __shared__ float smem[4];
    const int lane = threadIdx.x & 63;
    const int wave = threadIdx.x >> 6;
    if (lane == 0) smem[wave] = acc;
    __syncthreads();

    if (threadIdx.x == 0) {
        float s = smem[0] + smem[1] + smem[2] + smem[3];
        atomicAdd(out, s);
    }
}

extern "C" void kernel_launch(void* const* d_in, const int* in_sizes, int n_in,
                              void* d_out, int out_size, void* d_ws, size_t ws_size,
                              hipStream_t stream) {
    const float* pred = (const float*)d_in[0];   // N+1 floats
    const float* x    = (const float*)d_in[1];   // N floats
    const float* y    = (const float*)d_in[2];   // N floats
    float* out = (float*)d_out;

    const int n  = in_sizes[1];
    const int n4 = n >> 2;

    TrajLoss_zero_kernel<<<1, 64, 0, stream>>>(out);

    const int block = 256;
    const int grid  = 1024;          // 4 blocks/CU persistent
    const int stride = grid * block; // 262,144

    if ((n & 3) == 0 && n4 == 16 * stride) {
        // N = 16,777,216 path: exactly 16 chunks/thread, uniform lockstep.
        TrajLoss_6141803233879_kernel<<<grid, block, 0, stream>>>(pred, x, y, out, n);
    } else {
        TrajLoss_generic_kernel<<<grid, block, 0, stream>>>(pred, x, y, out, n4, n);
    }
}